// Round 7
// baseline (1167.014 us; speedup 1.0000x reference)
//
#include <hip/hip_runtime.h>
#include <stdint.h>

namespace {

constexpr int Tn = 512;
constexpr int Sn = 256;
constexpr float EPS = 1e-12f;

// Barrier that drains ONLY lgkmcnt (LDS), never vmcnt (T4 pattern).
__device__ __forceinline__ void wg_barrier_lds() {
    asm volatile("s_waitcnt lgkmcnt(0)" ::: "memory");
    __builtin_amdgcn_s_barrier();
}

__launch_bounds__(256, 1)
__global__ void hmm_kernel(const float* __restrict__ emission,  // [B,T,S]
                           const float* __restrict__ weight,    // [S,S]
                           const float* __restrict__ init,      // [S]
                           float* __restrict__ out)             // [B,T,S]
{
    const int j    = threadIdx.x;   // state / output column, 0..255
    const int b    = blockIdx.x;    // batch row
    const int wave = j >> 6;
    const int lane = j & 63;

    __shared__ __align__(16) float s_m[Sn];
    __shared__ __align__(16) float s_z[Sn];
    __shared__ __align__(16) float w_buf[2][Sn];   // double-buffered w~ vector
    __shared__ __align__(16) float partial[2][4];  // wave partials of sum(w~)

    // ---- prologue 1: transition softmax row stats ----
    {
        const float* wr = weight + j * Sn;
        float m = -3.402823466e38f;
        #pragma unroll
        for (int i = 0; i < Sn; i += 4) {
            float4 v = *reinterpret_cast<const float4*>(wr + i);
            m = fmaxf(m, fmaxf(fmaxf(v.x, v.y), fmaxf(v.z, v.w)));
        }
        float z0 = 0.f, z1 = 0.f, z2 = 0.f, z3 = 0.f;
        #pragma unroll
        for (int i = 0; i < Sn; i += 4) {
            float4 v = *reinterpret_cast<const float4*>(wr + i);
            z0 += expf(v.x - m); z1 += expf(v.y - m);
            z2 += expf(v.z - m); z3 += expf(v.w - m);
        }
        s_m[j] = m;
        s_z[j] = 1.f / ((z0 + z1) + (z2 + z3));
    }
    if (j < 8) reinterpret_cast<float*>(partial)[j] = 1.0f;  // t=0 dummy l1
    __syncthreads();

    // ---- prologue 2: transition column j -> registers (const-indexed) ----
    // MUST stay fully unrolled: tc[] lives in registers only while every
    // index is a compile-time constant (rule #20).
    float tc[Sn];
    #pragma unroll
    for (int k = 0; k < Sn; ++k)
        tc[k] = expf(weight[k * Sn + j] - s_m[k]) * s_z[k];
    __syncthreads();

    // ---- initial state softmax ----
    float u;
    {
        float x0 = init[j];
        float m0 = x0;
        #pragma unroll
        for (int o = 32; o >= 1; o >>= 1) m0 = fmaxf(m0, __shfl_xor(m0, o));
        if (lane == 0) s_m[wave] = m0;
        __syncthreads();
        m0 = fmaxf(fmaxf(s_m[0], s_m[1]), fmaxf(s_m[2], s_m[3]));
        float ex = expf(x0 - m0);
        float zz = ex;
        #pragma unroll
        for (int o = 32; o >= 1; o >>= 1) zz += __shfl_xor(zz, o);
        if (lane == 0) s_z[wave] = zz;
        __syncthreads();
        u = ex / ((s_z[0] + s_z[1]) + (s_z[2] + s_z[3]));
    }

    const float* em = emission + (size_t)b * Tn * Sn + j;
    float*       op = out      + (size_t)b * Tn * Sn + j;

    float wreg  = u * em[0];   // w~_0 (unnormalized from here on)
    float enext = em[Sn];      // e_1
    w_buf[0][j] = wreg;
    float acc_prev = 0.f;

// One MAC: w[K] broadcast via v_readlane (SGPR), tc[K] from registers.
// K is a compile-time constant: lane = K>>2, component = K&3.
#define FMA1(K, A)                                                        \
    A = fmaf(__int_as_float(__builtin_amdgcn_readlane(                    \
                 (((K) & 3) == 0 ? wi0 : ((K) & 3) == 1 ? wi1             \
                  : ((K) & 3) == 2 ? wi2 : wi3), (K) >> 2)),              \
             tc[(K)], A)

#define FMA8(Q) {                                                         \
        FMA1(8 * (Q) + 0, a0); FMA1(8 * (Q) + 1, a1);                     \
        FMA1(8 * (Q) + 2, a2); FMA1(8 * (Q) + 3, a3);                     \
        FMA1(8 * (Q) + 4, a4); FMA1(8 * (Q) + 5, a5);                     \
        FMA1(8 * (Q) + 6, a6); FMA1(8 * (Q) + 7, a7);                     \
    }
#define FMA32(Q) FMA8(Q) FMA8((Q)+1) FMA8((Q)+2) FMA8((Q)+3)

    // THE experiment: forbid unrolling of the 512-trip outer loop so the
    // ~600-instruction body stays ~4 KB and lives in L1 I$ across all
    // 512 iterations (suspected I-fetch starvation from full unroll).
    #pragma unroll 1
    for (int t = 0; t < Tn; ++t) {
        wg_barrier_lds();                // w~_t visible in w_buf[p]
        const int p = t & 1;

        // ONE distributed LDS read: lane l -> w[4l..4l+3] (whole vector/wave)
        const float4 wv4 = *reinterpret_cast<const float4*>(&w_buf[p][4 * lane]);
        const int wi0 = __float_as_int(wv4.x);
        const int wi1 = __float_as_int(wv4.y);
        const int wi2 = __float_as_int(wv4.z);
        const int wi3 = __float_as_int(wv4.w);

        // previous step's wave partials
        const float4 pp = *reinterpret_cast<const float4*>(partial[p ^ 1]);

        // prefetch e_{t+2} (global; stays in flight across lgkm-only barriers)
        const int tp = (t + 2 < Tn) ? (t + 2) : (Tn - 1);
        const float e2 = em[(size_t)tp * Sn];

        float a0 = 0.f, a1 = 0.f, a2 = 0.f, a3 = 0.f;
        float a4 = 0.f, a5 = 0.f, a6 = 0.f, a7 = 0.f;
        float r = wreg;                  // wave L1 reduce (w >= 0), interleaved

        FMA32(0)   r += __shfl_xor(r, 32);
        FMA32(4)   r += __shfl_xor(r, 16);
        FMA32(8)   r += __shfl_xor(r, 8);
        FMA32(12)  r += __shfl_xor(r, 4);
        FMA32(16)  r += __shfl_xor(r, 2);
        FMA32(20)  r += __shfl_xor(r, 1);
        FMA32(24)  if (lane == 0) partial[p][wave] = r;
        FMA32(28)

        // finish step t-1 (off critical path): l1 -> inv -> out store
        float l1  = fmaxf((pp.x + pp.y) + (pp.z + pp.w), EPS);
        float inv = 1.f / l1;
        const int ts = (t == 0) ? 0 : (t - 1);   // t=0 writes dummy, fixed at t=1
        op[(size_t)ts * Sn] = acc_prev * inv;

        // exact power-of-2 rescale (no rounding error, keeps magnitude sane)
        uint32_t ebits = __float_as_uint(l1) & 0x7f800000u;
        float sigma = __uint_as_float(0x7f000000u - ebits);

        float acc = ((a0 + a1) + (a2 + a3)) + ((a4 + a5) + (a6 + a7));
        acc_prev = acc;
        wreg = (acc * sigma) * enext;    // w~_{t+1}
        enext = e2;
        w_buf[p ^ 1][j] = wreg;
    }

    // epilogue: out_{T-1}
    wg_barrier_lds();
    {
        const float4 pp = *reinterpret_cast<const float4*>(partial[(Tn - 1) & 1]);
        float l1  = fmaxf((pp.x + pp.y) + (pp.z + pp.w), EPS);
        op[(size_t)(Tn - 1) * Sn] = acc_prev * (1.f / l1);
    }

#undef FMA1
#undef FMA8
#undef FMA32
}

} // namespace

extern "C" void kernel_launch(void* const* d_in, const int* in_sizes, int n_in,
                              void* d_out, int out_size, void* d_ws, size_t ws_size,
                              hipStream_t stream) {
    const float* emission = (const float*)d_in[0];
    const float* weight   = (const float*)d_in[1];
    const float* init     = (const float*)d_in[2];
    float* outp = (float*)d_out;
    const int Bn = in_sizes[0] / (Tn * Sn);   // 128 for the reference shapes

    hipLaunchKernelGGL(hmm_kernel, dim3(Bn), dim3(256), 0, stream,
                       emission, weight, init, outp);
}

// Round 8
// 743.381 us; speedup vs baseline: 1.5699x; 1.5699x over previous
//
#include <hip/hip_runtime.h>
#include <stdint.h>

namespace {

constexpr int Tn = 512;
constexpr int Sn = 256;
constexpr int NH = 4;          // k-split factor (slices)
constexpr int KS = Sn / NH;    // 64 k-values per slice
constexpr float EPS = 1e-12f;

// Barrier that drains ONLY lgkmcnt (LDS), never vmcnt (T4 pattern).
__device__ __forceinline__ void wg_barrier_lds() {
    asm volatile("s_waitcnt lgkmcnt(0)" ::: "memory");
    __builtin_amdgcn_s_barrier();
}

__launch_bounds__(1024, 4)
__global__ void hmm_kernel(const float* __restrict__ emission,  // [B,T,S]
                           const float* __restrict__ weight,    // [S,S]
                           const float* __restrict__ init,      // [S]
                           float* __restrict__ out)             // [B,T,S]
{
    const int tid  = threadIdx.x;
    const int j    = tid & 255;       // state / output column
    const int h    = tid >> 8;        // k-slice 0..3
    const int wv   = tid >> 6;        // wave 0..15
    const int lane = tid & 63;
    const int b    = blockIdx.x;      // batch row

    __shared__ __align__(16) float s_m[Sn];
    __shared__ __align__(16) float s_z[Sn];
    __shared__ __align__(16) float w_buf[2][Sn];     // double-buffered w~
    __shared__ __align__(16) float pacc[NH][Sn];     // per-slice GEMV partials
    __shared__ __align__(16) float partial[2][NH];   // per-slice L1 partials
    __shared__ __align__(16) float s_red[8];         // init-softmax scratch

    // ---- prologue 1: transition softmax row stats (4-way split) ----
    {
        const float* wr = weight + j * Sn + h * KS;
        float m = -3.402823466e38f;
        #pragma unroll
        for (int i = 0; i < KS; i += 4) {
            float4 v = *reinterpret_cast<const float4*>(wr + i);
            m = fmaxf(m, fmaxf(fmaxf(v.x, v.y), fmaxf(v.z, v.w)));
        }
        pacc[h][j] = m;
        __syncthreads();
        float mj = fmaxf(fmaxf(pacc[0][j], pacc[1][j]),
                         fmaxf(pacc[2][j], pacc[3][j]));
        float z0 = 0.f, z1 = 0.f, z2 = 0.f, z3 = 0.f;
        #pragma unroll
        for (int i = 0; i < KS; i += 4) {
            float4 v = *reinterpret_cast<const float4*>(wr + i);
            z0 += expf(v.x - mj); z1 += expf(v.y - mj);
            z2 += expf(v.z - mj); z3 += expf(v.w - mj);
        }
        __syncthreads();                 // everyone done reading pacc stage 1
        pacc[h][j] = (z0 + z1) + (z2 + z3);
        __syncthreads();
        if (h == 0) {
            s_m[j] = mj;
            s_z[j] = 1.f / (((pacc[0][j] + pacc[1][j]) +
                             (pacc[2][j] + pacc[3][j])));
        }
        __syncthreads();
    }

    // ---- prologue 2: my 64 transition-column entries -> registers ----
    // tc[i] = P[h*KS+i][j]; register indices are compile-time (rule #20).
    float tc[KS];
    #pragma unroll
    for (int i = 0; i < KS; ++i) {
        const int k = h * KS + i;
        tc[i] = expf(weight[k * Sn + j] - s_m[k]) * s_z[k];
    }

    // ---- initial state softmax (all threads compute; h0 uses) ----
    float u;
    {
        float x0 = init[j];
        float m0 = x0;
        #pragma unroll
        for (int o = 32; o >= 1; o >>= 1) m0 = fmaxf(m0, __shfl_xor(m0, o));
        if (h == 0 && lane == 0) s_red[wv] = m0;     // wv 0..3
        __syncthreads();
        m0 = fmaxf(fmaxf(s_red[0], s_red[1]), fmaxf(s_red[2], s_red[3]));
        float ex = expf(x0 - m0);
        float zz = ex;
        #pragma unroll
        for (int o = 32; o >= 1; o >>= 1) zz += __shfl_xor(zz, o);
        if (h == 0 && lane == 0) s_red[4 + wv] = zz;
        __syncthreads();
        u = ex / (((s_red[4] + s_red[5]) + (s_red[6] + s_red[7])));
    }

    const float* em = emission + (size_t)b * Tn * Sn + j;
    float*       op = out      + (size_t)b * Tn * Sn + j;

    float wreg = 0.f, enext = 0.f, acc_prev = 0.f;
    if (h == 0) {
        wreg  = u * em[0];          // w~_0 (unnormalized from here on)
        enext = em[Sn];             // e_1
        w_buf[0][j] = wreg;
    }
    if (tid < 8) reinterpret_cast<float*>(partial)[tid] = 1.0f;  // t=0 dummy

#define RL(I) __int_as_float(__builtin_amdgcn_readlane(wi, (I)))

    #pragma unroll 1
    for (int t = 0; t < Tn; ++t) {
        wg_barrier_lds();                       // B1: w~_t visible
        const int p = t & 1;

        // distributed slice read: lane l of slice h -> w[h*KS + l]
        const float wsl = w_buf[p][h * KS + lane];
        const int wi = __float_as_int(wsl);

        // per-slice partial GEMV: 64 readlane-broadcast MACs, 4 chains
        float p0 = 0.f, p1 = 0.f, p2 = 0.f, p3 = 0.f;
        #pragma unroll
        for (int q = 0; q < KS; q += 4) {
            p0 = fmaf(RL(q + 0), tc[q + 0], p0);
            p1 = fmaf(RL(q + 1), tc[q + 1], p1);
            p2 = fmaf(RL(q + 2), tc[q + 2], p2);
            p3 = fmaf(RL(q + 3), tc[q + 3], p3);
        }

        // slice L1 sum: one wave per slice (others overlap with FMAs)
        if ((wv & 3) == 0) {
            float r = wsl;
            #pragma unroll
            for (int o = 32; o >= 1; o >>= 1) r += __shfl_xor(r, o);
            if (lane == 0) partial[p][h] = r;
        }

        pacc[h][j] = (p0 + p1) + (p2 + p3);
        wg_barrier_lds();                       // B2: partials visible

        if (h == 0) {
            // combine 4 slice partials
            float acc = (pacc[0][j] + pacc[1][j]) + (pacc[2][j] + pacc[3][j]);

            // previous step's L1 (lagged, broadcast read)
            const float4 pp = *reinterpret_cast<const float4*>(partial[p ^ 1]);
            float l1  = fmaxf((pp.x + pp.y) + (pp.z + pp.w), EPS);
            float inv = 1.f / l1;
            const int ts = (t == 0) ? 0 : (t - 1);   // dummy at t=0, fixed at t=1
            op[(size_t)ts * Sn] = acc_prev * inv;

            // exact power-of-2 rescale (no rounding error)
            uint32_t ebits = __float_as_uint(l1) & 0x7f800000u;
            float sigma = __uint_as_float(0x7f000000u - ebits);

            // prefetch e_{t+2}
            const int tp = (t + 2 < Tn) ? (t + 2) : (Tn - 1);
            const float e2 = em[(size_t)tp * Sn];

            acc_prev = acc;
            wreg  = (acc * sigma) * enext;      // w~_{t+1}
            enext = e2;
            w_buf[p ^ 1][j] = wreg;
        }
    }

    // epilogue: out_{T-1}
    wg_barrier_lds();
    if (h == 0) {
        const float4 pp = *reinterpret_cast<const float4*>(partial[(Tn - 1) & 1]);
        float l1 = fmaxf((pp.x + pp.y) + (pp.z + pp.w), EPS);
        op[(size_t)(Tn - 1) * Sn] = acc_prev * (1.f / l1);
    }

#undef RL
}

} // namespace

extern "C" void kernel_launch(void* const* d_in, const int* in_sizes, int n_in,
                              void* d_out, int out_size, void* d_ws, size_t ws_size,
                              hipStream_t stream) {
    const float* emission = (const float*)d_in[0];
    const float* weight   = (const float*)d_in[1];
    const float* init     = (const float*)d_in[2];
    float* outp = (float*)d_out;
    const int Bn = in_sizes[0] / (Tn * Sn);   // 128 for the reference shapes

    hipLaunchKernelGGL(hmm_kernel, dim3(Bn), dim3(1024), 0, stream,
                       emission, weight, init, outp);
}

// Round 9
// 679.080 us; speedup vs baseline: 1.7185x; 1.0947x over previous
//
#include <hip/hip_runtime.h>
#include <stdint.h>

namespace {

constexpr int Tn = 512;
constexpr int Sn = 256;
constexpr int NH = 4;          // k-split factor (slices)
constexpr int KS = Sn / NH;    // 64 k-values per slice
constexpr float EPS = 1e-12f;

// Barrier that drains ONLY lgkmcnt (LDS), never vmcnt (T4 pattern).
__device__ __forceinline__ void wg_barrier_lds() {
    asm volatile("s_waitcnt lgkmcnt(0)" ::: "memory");
    __builtin_amdgcn_s_barrier();
}

__launch_bounds__(1024, 4)
__global__ void hmm_kernel(const float* __restrict__ emission,  // [B,T,S]
                           const float* __restrict__ weight,    // [S,S]
                           const float* __restrict__ init,      // [S]
                           float* __restrict__ out)             // [B,T,S]
{
    const int tid  = threadIdx.x;
    const int j    = tid & 255;       // output column this thread accumulates
    const int h    = tid >> 8;        // k-slice 0..3 (== wave>>2)
    const int wv   = tid >> 6;        // wave 0..15
    const int lane = tid & 63;
    const int c    = h * KS + lane;   // state column this thread CARRIES
    const int b    = blockIdx.x;      // batch row

    __shared__ __align__(16) float s_m[Sn];
    __shared__ __align__(16) float s_z[Sn];
    __shared__ __align__(16) float pacc[2][NH][Sn];  // dbuf GEMV partials
    __shared__ __align__(16) float partial[2][NH];   // dbuf slice L1 partials
    __shared__ __align__(16) float s_red[8];         // init-softmax scratch

    // ---- prologue 1: transition softmax row stats (4-way split over h) ----
    {
        const float* wr = weight + j * Sn + h * KS;
        float m = -3.402823466e38f;
        #pragma unroll
        for (int i = 0; i < KS; i += 4) {
            float4 v = *reinterpret_cast<const float4*>(wr + i);
            m = fmaxf(m, fmaxf(fmaxf(v.x, v.y), fmaxf(v.z, v.w)));
        }
        pacc[0][h][j] = m;
        __syncthreads();
        float mj = fmaxf(fmaxf(pacc[0][0][j], pacc[0][1][j]),
                         fmaxf(pacc[0][2][j], pacc[0][3][j]));
        float z0 = 0.f, z1 = 0.f, z2 = 0.f, z3 = 0.f;
        #pragma unroll
        for (int i = 0; i < KS; i += 4) {
            float4 v = *reinterpret_cast<const float4*>(wr + i);
            z0 += expf(v.x - mj); z1 += expf(v.y - mj);
            z2 += expf(v.z - mj); z3 += expf(v.w - mj);
        }
        __syncthreads();
        pacc[0][h][j] = (z0 + z1) + (z2 + z3);
        __syncthreads();
        if (h == 0) {
            s_m[j] = mj;
            s_z[j] = 1.f / ((pacc[0][0][j] + pacc[0][1][j]) +
                            (pacc[0][2][j] + pacc[0][3][j]));
        }
        __syncthreads();
    }

    // ---- prologue 2: my 64 transition entries -> registers ----
    // tc[i] = P[h*KS+i][j]; compile-time register indices (rule #20).
    float tc[KS];
    #pragma unroll
    for (int i = 0; i < KS; ++i) {
        const int k = h * KS + i;
        tc[i] = expf(weight[k * Sn + j] - s_m[k]) * s_z[k];
    }

    // ---- initial state softmax, evaluated at carried column c ----
    float u;
    {
        float x0 = init[c];
        float m0 = x0;   // wave holds slice h of init across lanes
        #pragma unroll
        for (int o = 32; o >= 1; o >>= 1) m0 = fmaxf(m0, __shfl_xor(m0, o));
        if ((wv & 3) == 0 && lane == 0) s_red[h] = m0;
        __syncthreads();
        m0 = fmaxf(fmaxf(s_red[0], s_red[1]), fmaxf(s_red[2], s_red[3]));
        float ex = expf(x0 - m0);
        float zz = ex;
        #pragma unroll
        for (int o = 32; o >= 1; o >>= 1) zz += __shfl_xor(zz, o);
        if ((wv & 3) == 0 && lane == 0) s_red[4 + h] = zz;
        __syncthreads();
        u = ex / ((s_red[4] + s_red[5]) + (s_red[6] + s_red[7]));
    }

    // per-thread streams at carried column c
    const float* em = emission + (size_t)b * Tn * Sn + c;
    float*       op = out      + (size_t)b * Tn * Sn + c;

    float wreg  = u * em[0];      // w~_0[c] (unnormalized recursion)
    float enext = em[Sn];         // e_1[c]

#define RL(I) __int_as_float(__builtin_amdgcn_readlane(wi, (I)))

    #pragma unroll 1
    for (int t = 0; t < Tn; ++t) {
        const int p = t & 1;
        const int wi = __float_as_int(wreg);   // own-wave broadcast source

        // partial GEMV for output column j over slice h:
        //   pacc = sum_i w~[h*64+i] * P[h*64+i][j], w~ via readlane (no LDS!)
        float p0 = 0.f, p1 = 0.f, p2 = 0.f, p3 = 0.f;
        #pragma unroll
        for (int q = 0; q < KS; q += 4) {
            p0 = fmaf(RL(q + 0), tc[q + 0], p0);
            p1 = fmaf(RL(q + 1), tc[q + 1], p1);
            p2 = fmaf(RL(q + 2), tc[q + 2], p2);
            p3 = fmaf(RL(q + 3), tc[q + 3], p3);
        }

        // slice L1: lanes of this wave hold the whole slice-h w-vector
        float r = wreg;
        #pragma unroll
        for (int o = 32; o >= 1; o >>= 1) r += __shfl_xor(r, o);

        pacc[p][h][j] = (p0 + p1) + (p2 + p3);
        if ((wv & 3) == 0 && lane == 0) partial[p][h] = r;

        wg_barrier_lds();                    // the ONLY barrier per step

        // every thread finishes its carried column c
        float a = (pacc[p][0][c] + pacc[p][1][c]) +
                  (pacc[p][2][c] + pacc[p][3][c]);
        const float4 pl = *reinterpret_cast<const float4*>(partial[p]);
        float l1  = fmaxf((pl.x + pl.y) + (pl.z + pl.w), EPS);
        float inv = 1.f / l1;

        if ((wv & 3) == 0)                   // one wave per slice stores
            op[(size_t)t * Sn] = a * inv;    // out_t[c] = normalize(acc)[c]

        // exact power-of-2 rescale keeps w~ bounded, zero rounding error
        uint32_t ebits = __float_as_uint(l1) & 0x7f800000u;
        float sigma = __uint_as_float(0x7f000000u - ebits);

        // prefetch e_{t+2}[c]
        const int tp = (t + 2 < Tn) ? (t + 2) : (Tn - 1);
        const float e2 = em[(size_t)tp * Sn];

        wreg  = (a * sigma) * enext;         // w~_{t+1}[c]
        enext = e2;
    }

#undef RL
}

} // namespace

extern "C" void kernel_launch(void* const* d_in, const int* in_sizes, int n_in,
                              void* d_out, int out_size, void* d_ws, size_t ws_size,
                              hipStream_t stream) {
    const float* emission = (const float*)d_in[0];
    const float* weight   = (const float*)d_in[1];
    const float* init     = (const float*)d_in[2];
    float* outp = (float*)d_out;
    const int Bn = in_sizes[0] / (Tn * Sn);   // 128 for the reference shapes

    hipLaunchKernelGGL(hmm_kernel, dim3(Bn), dim3(1024), 0, stream,
                       emission, weight, init, outp);
}

// Round 10
// 662.857 us; speedup vs baseline: 1.7606x; 1.0245x over previous
//
#include <hip/hip_runtime.h>
#include <stdint.h>

namespace {

constexpr int Tn = 512;
constexpr int Sn = 256;
constexpr int NH = 4;          // k-split factor (slices)
constexpr int KS = Sn / NH;    // 64 k-values per slice
constexpr float EPS = 1e-12f;

// Barrier that drains ONLY lgkmcnt (LDS), never vmcnt (T4 pattern).
__device__ __forceinline__ void wg_barrier_lds() {
    asm volatile("s_waitcnt lgkmcnt(0)" ::: "memory");
    __builtin_amdgcn_s_barrier();
}

// 64-lane sum via DPP row ops — pure VALU (no LDS pipe, no lgkmcnt).
// After the 6 adds, lane 63 holds the full-wave sum.
__device__ __forceinline__ float wave_sum_dpp(float x) {
#define DPP_ADD(CTRL)                                                     \
    x += __int_as_float(__builtin_amdgcn_update_dpp(                      \
            0, __float_as_int(x), (CTRL), 0xf, 0xf, true))
    DPP_ADD(0x111);   // row_shr:1
    DPP_ADD(0x112);   // row_shr:2
    DPP_ADD(0x114);   // row_shr:4
    DPP_ADD(0x118);   // row_shr:8   -> lane 15 of each row16 has row sum
    DPP_ADD(0x142);   // row_bcast:15 -> lane31 = sum(0..31), lane63 = sum(32..63)
    DPP_ADD(0x143);   // row_bcast:31 -> lane63 = sum(0..63)
#undef DPP_ADD
    return x;
}

__launch_bounds__(1024, 4)
__global__ void hmm_kernel(const float* __restrict__ emission,  // [B,T,S]
                           const float* __restrict__ weight,    // [S,S]
                           const float* __restrict__ init,      // [S]
                           float* __restrict__ out)             // [B,T,S]
{
    const int tid  = threadIdx.x;
    const int j    = tid & 255;       // output column this thread accumulates
    const int h    = tid >> 8;        // k-slice 0..3
    const int wv   = tid >> 6;        // wave 0..15
    const int lane = tid & 63;
    const int c    = h * KS + lane;   // state column this thread CARRIES
    const int b    = blockIdx.x;      // batch row

    __shared__ __align__(16) float s_m[Sn];
    __shared__ __align__(16) float s_z[Sn];
    __shared__ __align__(16) float pacc[2][NH][Sn];  // dbuf GEMV partials
    __shared__ __align__(16) float partial[2][NH];   // dbuf slice L1 partials
    __shared__ __align__(16) float s_red[8];         // init-softmax scratch

    // ---- prologue 1: transition softmax row stats (4-way split over h) ----
    {
        const float* wr = weight + j * Sn + h * KS;
        float m = -3.402823466e38f;
        #pragma unroll
        for (int i = 0; i < KS; i += 4) {
            float4 v = *reinterpret_cast<const float4*>(wr + i);
            m = fmaxf(m, fmaxf(fmaxf(v.x, v.y), fmaxf(v.z, v.w)));
        }
        pacc[0][h][j] = m;
        __syncthreads();
        float mj = fmaxf(fmaxf(pacc[0][0][j], pacc[0][1][j]),
                         fmaxf(pacc[0][2][j], pacc[0][3][j]));
        float z0 = 0.f, z1 = 0.f, z2 = 0.f, z3 = 0.f;
        #pragma unroll
        for (int i = 0; i < KS; i += 4) {
            float4 v = *reinterpret_cast<const float4*>(wr + i);
            z0 += expf(v.x - mj); z1 += expf(v.y - mj);
            z2 += expf(v.z - mj); z3 += expf(v.w - mj);
        }
        __syncthreads();
        pacc[0][h][j] = (z0 + z1) + (z2 + z3);
        __syncthreads();
        if (h == 0) {
            s_m[j] = mj;
            s_z[j] = 1.f / ((pacc[0][0][j] + pacc[0][1][j]) +
                            (pacc[0][2][j] + pacc[0][3][j]));
        }
        __syncthreads();
    }

    // ---- prologue 2: my 64 transition entries -> registers ----
    // tc[i] = P[h*KS+i][j]; compile-time register indices (rule #20).
    float tc[KS];
    #pragma unroll
    for (int i = 0; i < KS; ++i) {
        const int k = h * KS + i;
        tc[i] = expf(weight[k * Sn + j] - s_m[k]) * s_z[k];
    }

    // ---- initial state softmax, evaluated at carried column c ----
    float u;
    {
        float x0 = init[c];
        float m0 = x0;
        #pragma unroll
        for (int o = 32; o >= 1; o >>= 1) m0 = fmaxf(m0, __shfl_xor(m0, o));
        if ((wv & 3) == 0 && lane == 0) s_red[h] = m0;
        __syncthreads();
        m0 = fmaxf(fmaxf(s_red[0], s_red[1]), fmaxf(s_red[2], s_red[3]));
        float ex = expf(x0 - m0);
        float zz = ex;
        #pragma unroll
        for (int o = 32; o >= 1; o >>= 1) zz += __shfl_xor(zz, o);
        if ((wv & 3) == 0 && lane == 0) s_red[4 + h] = zz;
        __syncthreads();
        u = ex / ((s_red[4] + s_red[5]) + (s_red[6] + s_red[7]));
    }

    // per-thread streams at carried column c
    const float* em = emission + (size_t)b * Tn * Sn + c;
    float*       op = out      + (size_t)b * Tn * Sn + c;

    float wreg  = u * em[0];      // w~_0[c] (unnormalized recursion)
    float enext = em[Sn];         // e_1[c]

#define RL(I) __int_as_float(__builtin_amdgcn_readlane(wi, (I)))

    #pragma unroll 1
    for (int t = 0; t < Tn; ++t) {
        const int p = t & 1;
        const int wi = __float_as_int(wreg);   // own-wave broadcast source

        // partial GEMV for output column j over slice h:
        //   pacc = sum_i w~[h*64+i] * P[h*64+i][j], w~ via readlane (no LDS)
        float p0 = 0.f, p1 = 0.f, p2 = 0.f, p3 = 0.f;
        #pragma unroll
        for (int q = 0; q < KS; q += 4) {
            p0 = fmaf(RL(q + 0), tc[q + 0], p0);
            p1 = fmaf(RL(q + 1), tc[q + 1], p1);
            p2 = fmaf(RL(q + 2), tc[q + 2], p2);
            p3 = fmaf(RL(q + 3), tc[q + 3], p3);
        }

        // slice L1 sum: DPP (pure VALU), only the 4 storing waves bother
        if ((wv & 3) == 0) {
            float r = wave_sum_dpp(wreg);
            if (lane == 63) partial[p][h] = r;
        }

        pacc[p][h][j] = (p0 + p1) + (p2 + p3);

        wg_barrier_lds();                    // the ONLY barrier per step

        // every thread finishes its carried column c
        float a = (pacc[p][0][c] + pacc[p][1][c]) +
                  (pacc[p][2][c] + pacc[p][3][c]);
        const float4 pl = *reinterpret_cast<const float4*>(partial[p]);
        float l1  = fmaxf((pl.x + pl.y) + (pl.z + pl.w), EPS);
        float inv = 1.f / l1;

        if ((wv & 3) == 0)                   // one wave per slice stores
            op[(size_t)t * Sn] = a * inv;    // out_t[c] = normalize(acc)[c]

        // exact power-of-2 rescale keeps w~ bounded, zero rounding error
        uint32_t ebits = __float_as_uint(l1) & 0x7f800000u;
        float sigma = __uint_as_float(0x7f000000u - ebits);

        // prefetch e_{t+2}[c]
        const int tp = (t + 2 < Tn) ? (t + 2) : (Tn - 1);
        const float e2 = em[(size_t)tp * Sn];

        wreg  = (a * sigma) * enext;         // w~_{t+1}[c]
        enext = e2;
    }

#undef RL
}

} // namespace

extern "C" void kernel_launch(void* const* d_in, const int* in_sizes, int n_in,
                              void* d_out, int out_size, void* d_ws, size_t ws_size,
                              hipStream_t stream) {
    const float* emission = (const float*)d_in[0];
    const float* weight   = (const float*)d_in[1];
    const float* init     = (const float*)d_in[2];
    float* outp = (float*)d_out;
    const int Bn = in_sizes[0] / (Tn * Sn);   // 128 for the reference shapes

    hipLaunchKernelGGL(hmm_kernel, dim3(Bn), dim3(1024), 0, stream,
                       emission, weight, init, outp);
}

// Round 11
// 465.395 us; speedup vs baseline: 2.5076x; 1.4243x over previous
//
#include <hip/hip_runtime.h>
#include <stdint.h>

namespace {

constexpr int Tn = 512;
constexpr int Sn = 256;
constexpr float EPS = 1e-12f;

typedef _Float16 f16x8 __attribute__((ext_vector_type(8)));
typedef float    f32x4 __attribute__((ext_vector_type(4)));

// Barrier that drains ONLY lgkmcnt (LDS), never vmcnt (T4 pattern).
__device__ __forceinline__ void wg_barrier_lds() {
    asm volatile("s_waitcnt lgkmcnt(0)" ::: "memory");
    __builtin_amdgcn_s_barrier();
}

// Sum within each 16-lane group via DPP row_shr; lane 15 (mod 16) holds sum.
__device__ __forceinline__ float group16_sum_dpp(float x) {
#define DPP_ADD(CTRL)                                                      \
    x += __int_as_float(__builtin_amdgcn_update_dpp(                       \
            0, __float_as_int(x), (CTRL), 0xf, 0xf, true))
    DPP_ADD(0x111);  // row_shr:1
    DPP_ADD(0x112);  // row_shr:2
    DPP_ADD(0x114);  // row_shr:4
    DPP_ADD(0x118);  // row_shr:8
#undef DPP_ADD
    return x;
}

__launch_bounds__(1024, 4)
__global__ void hmm_kernel(const float* __restrict__ emission,  // [B,T,S]
                           const float* __restrict__ weight,    // [S,S]
                           const float* __restrict__ init,      // [S]
                           float* __restrict__ out)             // [B,T,S]
{
    const int tid  = threadIdx.x;
    const int wv   = tid >> 6;        // wave 0..15: owns output cols 16wv..16wv+15
    const int lane = tid & 63;
    const int g    = lane >> 4;       // k-lane-group 0..3
    const int jj   = lane & 15;       // col within the wave's block
    const int c    = 16 * wv + jj;    // this lane's column (replicated over g)
    const int b    = blockIdx.x;      // batch row

    __shared__ __align__(16) _Float16 wf16[2][Sn];   // dbuf w~ image (f16)
    __shared__ __align__(16) float    part[2][16];   // dbuf per-wave L1 partials
    __shared__ __align__(16) float    s_m[Sn];
    __shared__ __align__(16) float    s_z[Sn];
    __shared__ __align__(16) float    scr[4][Sn];    // prologue scratch

    // ---- prologue 1: transition softmax row stats ----
    {
        const int j = tid & 255, h = tid >> 8;
        const float* wr = weight + j * Sn + h * 64;
        float m = -3.402823466e38f;
        #pragma unroll
        for (int i = 0; i < 64; i += 4) {
            float4 v = *reinterpret_cast<const float4*>(wr + i);
            m = fmaxf(m, fmaxf(fmaxf(v.x, v.y), fmaxf(v.z, v.w)));
        }
        scr[h][j] = m;
        __syncthreads();
        float mj = fmaxf(fmaxf(scr[0][j], scr[1][j]),
                         fmaxf(scr[2][j], scr[3][j]));
        float z0 = 0.f, z1 = 0.f, z2 = 0.f, z3 = 0.f;
        #pragma unroll
        for (int i = 0; i < 64; i += 4) {
            float4 v = *reinterpret_cast<const float4*>(wr + i);
            z0 += expf(v.x - mj); z1 += expf(v.y - mj);
            z2 += expf(v.z - mj); z3 += expf(v.w - mj);
        }
        __syncthreads();
        scr[h][j] = (z0 + z1) + (z2 + z3);
        __syncthreads();
        if (h == 0) {
            s_m[j] = mj;
            s_z[j] = 1.f / ((scr[0][j] + scr[1][j]) + (scr[2][j] + scr[3][j]));
        }
        __syncthreads();
    }

    // ---- prologue 2: persistent B fragments (P columns, f16) ----
    // Convention (used identically for A below): chunk ck, lane-group g,
    // elem i  <->  k = ck*32 + g*8 + i.  A/B layout symmetry makes the
    // contraction correct under any hardware k-slot permutation.
    f16x8 bf[8];
    #pragma unroll
    for (int ck = 0; ck < 8; ++ck) {
        #pragma unroll
        for (int i = 0; i < 8; ++i) {
            const int k = ck * 32 + g * 8 + i;
            float pv = expf(weight[k * Sn + c] - s_m[k]) * s_z[k];
            bf[ck][i] = (_Float16)pv;
        }
    }

    // ---- prologue 3: initial state softmax -> w~_0, e_1, LDS image ----
    const float* em = emission + (size_t)b * Tn * Sn + c;
    float*       op = out      + (size_t)b * Tn * Sn + c;
    {
        float i0 = init[lane], i1 = init[lane + 64],
              i2 = init[lane + 128], i3 = init[lane + 192];
        float mx = fmaxf(fmaxf(i0, i1), fmaxf(i2, i3));
        #pragma unroll
        for (int o = 32; o >= 1; o >>= 1) mx = fmaxf(mx, __shfl_xor(mx, o));
        float zz = expf(i0 - mx) + expf(i1 - mx) + expf(i2 - mx) + expf(i3 - mx);
        #pragma unroll
        for (int o = 32; o >= 1; o >>= 1) zz += __shfl_xor(zz, o);
        float u  = expf(init[c] - mx) / zz;
        float w0 = u * em[0];
        if (g == 0) wf16[0][c] = (_Float16)w0;
        float r = group16_sum_dpp(w0);
        if (g == 0 && jj == 15) part[0][wv] = r;
    }
    float enext = em[Sn];          // e_1[c]
    __syncthreads();

#define MFMA(A, B, D) __builtin_amdgcn_mfma_f32_16x16x32_f16((A), (B), (D), 0, 0, 0)

    #pragma unroll 1
    for (int t = 0; t < Tn; ++t) {
        const int p = t & 1;

        // A fragments: w~_t image, broadcast into all 16 M-rows
        f16x8 af[8];
        #pragma unroll
        for (int ck = 0; ck < 8; ++ck)
            af[ck] = *reinterpret_cast<const f16x8*>(&wf16[p][ck * 32 + g * 8]);

        // L1(w~_t) from the 16 per-wave partials (broadcast b128 reads)
        const f32x4* pp4 = reinterpret_cast<const f32x4*>(part[p]);
        f32x4 q = (pp4[0] + pp4[1]) + (pp4[2] + pp4[3]);
        float l1 = fmaxf((q.x + q.y) + (q.z + q.w), EPS);

        // y = w~_t @ P  for this wave's 16 columns (two chains of 4 MFMAs)
        f32x4 da = {0.f, 0.f, 0.f, 0.f}, db = {0.f, 0.f, 0.f, 0.f};
        da = MFMA(af[0], bf[0], da);  db = MFMA(af[4], bf[4], db);
        da = MFMA(af[1], bf[1], da);  db = MFMA(af[5], bf[5], db);
        da = MFMA(af[2], bf[2], da);  db = MFMA(af[6], bf[6], db);
        da = MFMA(af[3], bf[3], da);  db = MFMA(af[7], bf[7], db);
        float y = da[0] + db[0];      // row-broadcast A => reg0 = y[c] in every lane

        // out_t = y / l1 (store by one lane-group)
        float inv = 1.f / l1;
        if (g == 0) op[(size_t)t * Sn] = y * inv;

        // exact power-of-2 rescale; Bayes update to w~_{t+1}
        uint32_t ebits = __float_as_uint(l1) & 0x7f800000u;
        float sigma = __uint_as_float(0x7f000000u - ebits);

        const int tp = (t + 2 < Tn) ? (t + 2) : (Tn - 1);
        const float e2 = em[(size_t)tp * Sn];   // prefetch e_{t+2}

        float wn = (y * sigma) * enext;         // w~_{t+1}[c]
        enext = e2;

        if (g == 0) wf16[p ^ 1][c] = (_Float16)wn;
        float r = group16_sum_dpp(wn);
        if (g == 0 && jj == 15) part[p ^ 1][wv] = r;

        wg_barrier_lds();     // single lgkm-only barrier per step
    }

#undef MFMA
}

} // namespace

extern "C" void kernel_launch(void* const* d_in, const int* in_sizes, int n_in,
                              void* d_out, int out_size, void* d_ws, size_t ws_size,
                              hipStream_t stream) {
    const float* emission = (const float*)d_in[0];
    const float* weight   = (const float*)d_in[1];
    const float* init     = (const float*)d_in[2];
    float* outp = (float*)d_out;
    const int Bn = in_sizes[0] / (Tn * Sn);   // 128 for the reference shapes

    hipLaunchKernelGGL(hmm_kernel, dim3(Bn), dim3(1024), 0, stream,
                       emission, weight, init, outp);
}

// Round 12
// 371.855 us; speedup vs baseline: 3.1384x; 1.2515x over previous
//
#include <hip/hip_runtime.h>
#include <stdint.h>

namespace {

constexpr int Tn = 512;
constexpr int Sn = 256;
constexpr float EPS = 1e-12f;

typedef _Float16 f16x8 __attribute__((ext_vector_type(8)));
typedef float    f32x4 __attribute__((ext_vector_type(4)));

// Barrier that drains ONLY lgkmcnt (LDS), never vmcnt (T4 pattern).
__device__ __forceinline__ void wg_barrier_lds() {
    asm volatile("s_waitcnt lgkmcnt(0)" ::: "memory");
    __builtin_amdgcn_s_barrier();
}

// Sum lanes 0..31 into lane 31 (and 32..63 into lane 63) — pure-VALU DPP.
__device__ __forceinline__ float sum32_dpp(float x) {
#define DPP_ADD(CTRL)                                                      \
    x += __int_as_float(__builtin_amdgcn_update_dpp(                       \
            0, __float_as_int(x), (CTRL), 0xf, 0xf, true))
    DPP_ADD(0x111);  // row_shr:1
    DPP_ADD(0x112);  // row_shr:2
    DPP_ADD(0x114);  // row_shr:4
    DPP_ADD(0x118);  // row_shr:8   -> lane15 = sum(0..15), lane31 = sum(16..31)
    DPP_ADD(0x142);  // row_bcast:15 -> lane31 = sum(0..31)
#undef DPP_ADD
    return x;
}

__launch_bounds__(512, 2)
__global__ void hmm_kernel(const float* __restrict__ emission,  // [B,T,S]
                           const float* __restrict__ weight,    // [S,S]
                           const float* __restrict__ init,      // [S]
                           float* __restrict__ out)             // [B,T,S]
{
    const int tid  = threadIdx.x;
    const int wv   = tid >> 6;         // wave 0..7: owns cols 32wv .. 32wv+31
    const int lane = tid & 63;
    const int g    = lane >> 4;        // k-lane-group 0..3
    const int jj   = lane & 15;
    const int cA   = 32 * wv + jj;     // col-set A column
    const int cB   = cA + 16;          // col-set B column
    const int c32  = 32 * wv + (lane & 31);   // carried column (lanes < 32)
    const int b    = blockIdx.x;

    __shared__ __align__(16) _Float16 wf16[2][Sn];   // dbuf w~ image (f16)
    __shared__ __align__(16) float    part[2][8];    // dbuf per-wave L1 partials
    __shared__ __align__(16) float    s_m[Sn];
    __shared__ __align__(16) float    s_z[Sn];
    __shared__ __align__(16) float    scr[2][Sn];    // prologue scratch

    // ---- prologue 1: transition softmax row stats (512 threads, 2 halves) ----
    {
        const int j = tid & 255, h = tid >> 8;       // h in {0,1}
        const float* wr = weight + j * Sn + h * 128;
        float m = -3.402823466e38f;
        #pragma unroll
        for (int i = 0; i < 128; i += 4) {
            float4 v = *reinterpret_cast<const float4*>(wr + i);
            m = fmaxf(m, fmaxf(fmaxf(v.x, v.y), fmaxf(v.z, v.w)));
        }
        scr[h][j] = m;
        __syncthreads();
        float mj = fmaxf(scr[0][j], scr[1][j]);
        float z0 = 0.f, z1 = 0.f, z2 = 0.f, z3 = 0.f;
        #pragma unroll
        for (int i = 0; i < 128; i += 4) {
            float4 v = *reinterpret_cast<const float4*>(wr + i);
            z0 += expf(v.x - mj); z1 += expf(v.y - mj);
            z2 += expf(v.z - mj); z3 += expf(v.w - mj);
        }
        __syncthreads();
        scr[h][j] = (z0 + z1) + (z2 + z3);
        __syncthreads();
        if (h == 0) {
            s_m[j] = mj;
            s_z[j] = 1.f / (scr[0][j] + scr[1][j]);
        }
        __syncthreads();
    }

    // ---- prologue 2: persistent B fragments for BOTH col-sets (f16) ----
    // Shared k-convention with A: chunk ck, group g, elem i <-> k = ck*32+g*8+i.
    f16x8 bfA[8], bfB[8];
    #pragma unroll
    for (int ck = 0; ck < 8; ++ck) {
        #pragma unroll
        for (int i = 0; i < 8; ++i) {
            const int k = ck * 32 + g * 8 + i;
            const float* wk = weight + (size_t)k * Sn;
            bfA[ck][i] = (_Float16)(expf(wk[cA] - s_m[k]) * s_z[k]);
            bfB[ck][i] = (_Float16)(expf(wk[cB] - s_m[k]) * s_z[k]);
        }
    }

    // ---- prologue 3: initial state softmax -> w~_0, e_1, LDS image ----
    const float* em = emission + (size_t)b * Tn * Sn + c32;
    float*       op = out      + (size_t)b * Tn * Sn + c32;
    {
        float i0 = init[lane], i1 = init[lane + 64],
              i2 = init[lane + 128], i3 = init[lane + 192];
        float mx = fmaxf(fmaxf(i0, i1), fmaxf(i2, i3));
        #pragma unroll
        for (int o = 32; o >= 1; o >>= 1) mx = fmaxf(mx, __shfl_xor(mx, o));
        float zz = expf(i0 - mx) + expf(i1 - mx) + expf(i2 - mx) + expf(i3 - mx);
        #pragma unroll
        for (int o = 32; o >= 1; o >>= 1) zz += __shfl_xor(zz, o);
        float u  = expf(init[c32] - mx) / zz;
        float w0 = u * em[0];
        if (lane < 32) wf16[0][c32] = (_Float16)w0;
        float r = sum32_dpp(w0);
        if (lane == 31) part[0][wv] = r;
    }
    float enext = em[Sn];          // e_1[c32]
    __syncthreads();

#define MFMA(A, B, D) __builtin_amdgcn_mfma_f32_16x16x32_f16((A), (B), (D), 0, 0, 0)

    #pragma unroll 1
    for (int t = 0; t < Tn; ++t) {
        const int p = t & 1;

        // A fragments: w~_t image broadcast into all 16 M-rows (8 b128 reads,
        // shared between both col-sets)
        f16x8 af[8];
        #pragma unroll
        for (int ck = 0; ck < 8; ++ck)
            af[ck] = *reinterpret_cast<const f16x8*>(&wf16[p][ck * 32 + g * 8]);

        // L1(w~_t) from 8 per-wave partials (2 broadcast b128 reads)
        const f32x4* pp4 = reinterpret_cast<const f32x4*>(part[p]);
        f32x4 q = pp4[0] + pp4[1];
        float l1 = fmaxf((q.x + q.y) + (q.z + q.w), EPS);

        // y = w~_t @ P for 32 columns: 16 MFMAs, 4 independent chains of 4
        f32x4 dA0 = {0.f,0.f,0.f,0.f}, dA1 = {0.f,0.f,0.f,0.f};
        f32x4 dB0 = {0.f,0.f,0.f,0.f}, dB1 = {0.f,0.f,0.f,0.f};
        dA0 = MFMA(af[0], bfA[0], dA0);  dB0 = MFMA(af[0], bfB[0], dB0);
        dA1 = MFMA(af[4], bfA[4], dA1);  dB1 = MFMA(af[4], bfB[4], dB1);
        dA0 = MFMA(af[1], bfA[1], dA0);  dB0 = MFMA(af[1], bfB[1], dB0);
        dA1 = MFMA(af[5], bfA[5], dA1);  dB1 = MFMA(af[5], bfB[5], dB1);
        dA0 = MFMA(af[2], bfA[2], dA0);  dB0 = MFMA(af[2], bfB[2], dB0);
        dA1 = MFMA(af[6], bfA[6], dA1);  dB1 = MFMA(af[6], bfB[6], dB1);
        dA0 = MFMA(af[3], bfA[3], dA0);  dB0 = MFMA(af[3], bfB[3], dB0);
        dA1 = MFMA(af[7], bfA[7], dA1);  dB1 = MFMA(af[7], bfB[7], dB1);

        // row-broadcast A => reg0 of every lane holds y[col-set[jj]]
        float yA = dA0[0] + dA1[0];
        float yB = dB0[0] + dB1[0];
        float y  = (lane < 16) ? yA : yB;      // lanes 0..31 cover all 32 cols

        float inv = 1.f / l1;
        if (lane < 32) op[(size_t)t * Sn] = y * inv;   // out_t = normalize

        // exact power-of-2 rescale; Bayes update to w~_{t+1}
        uint32_t ebits = __float_as_uint(l1) & 0x7f800000u;
        float sigma = __uint_as_float(0x7f000000u - ebits);

        const int tp = (t + 2 < Tn) ? (t + 2) : (Tn - 1);
        const float e2 = em[(size_t)tp * Sn];   // prefetch e_{t+2}

        float wn = (y * sigma) * enext;         // w~_{t+1}[c32] (lanes<32 valid)
        enext = e2;

        if (lane < 32) wf16[p ^ 1][c32] = (_Float16)wn;
        float r = sum32_dpp(wn);
        if (lane == 31) part[p ^ 1][wv] = r;

        wg_barrier_lds();     // single lgkm-only barrier per step
    }

#undef MFMA
}

} // namespace

extern "C" void kernel_launch(void* const* d_in, const int* in_sizes, int n_in,
                              void* d_out, int out_size, void* d_ws, size_t ws_size,
                              hipStream_t stream) {
    const float* emission = (const float*)d_in[0];
    const float* weight   = (const float*)d_in[1];
    const float* init     = (const float*)d_in[2];
    float* outp = (float*)d_out;
    const int Bn = in_sizes[0] / (Tn * Sn);   // 128 for the reference shapes

    hipLaunchKernelGGL(hmm_kernel, dim3(Bn), dim3(512), 0, stream,
                       emission, weight, init, outp);
}

// Round 14
// 336.445 us; speedup vs baseline: 3.4687x; 1.1052x over previous
//
#include <hip/hip_runtime.h>
#include <stdint.h>

namespace {

constexpr int Tn = 512;
constexpr int Sn = 256;
constexpr float EPS = 1e-12f;

typedef _Float16 f16x8 __attribute__((ext_vector_type(8)));
typedef float    f32x4 __attribute__((ext_vector_type(4)));

// Barrier that drains ONLY lgkmcnt (LDS), never vmcnt (T4 pattern).
__device__ __forceinline__ void wg_barrier_lds() {
    asm volatile("s_waitcnt lgkmcnt(0)" ::: "memory");
    __builtin_amdgcn_s_barrier();
}

__launch_bounds__(512, 2)
__global__ void hmm_kernel(const float* __restrict__ emission,  // [B,T,S]
                           const float* __restrict__ weight,    // [S,S]
                           const float* __restrict__ init,      // [S]
                           float* __restrict__ out)             // [B,T,S]
{
    const int tid  = threadIdx.x;
    const int wv   = tid >> 6;         // wave 0..7: owns cols 32wv .. 32wv+31
    const int lane = tid & 63;
    const int g    = lane >> 4;        // k-lane-group 0..3
    const int jj   = lane & 15;
    const int cA   = 32 * wv + jj;     // col-set A column
    const int cB   = cA + 16;          // col-set B column
    const int c32  = 32 * wv + (lane & 31);   // carried column
    const int b    = blockIdx.x;

    __shared__ __align__(16) _Float16 wf16[2][Sn];   // dbuf w~ image (f16)
    __shared__ __align__(16) float    s_m[Sn];
    __shared__ __align__(16) float    s_z[Sn];
    __shared__ __align__(16) float    scr[2][Sn];    // prologue scratch

    // ---- prologue 1: transition softmax row stats (512 threads, 2 halves) ----
    {
        const int j = tid & 255, h = tid >> 8;       // h in {0,1}
        const float* wr = weight + j * Sn + h * 128;
        float m = -3.402823466e38f;
        #pragma unroll
        for (int i = 0; i < 128; i += 4) {
            float4 v = *reinterpret_cast<const float4*>(wr + i);
            m = fmaxf(m, fmaxf(fmaxf(v.x, v.y), fmaxf(v.z, v.w)));
        }
        scr[h][j] = m;
        __syncthreads();
        float mj = fmaxf(scr[0][j], scr[1][j]);
        float z0 = 0.f, z1 = 0.f, z2 = 0.f, z3 = 0.f;
        #pragma unroll
        for (int i = 0; i < 128; i += 4) {
            float4 v = *reinterpret_cast<const float4*>(wr + i);
            z0 += expf(v.x - mj); z1 += expf(v.y - mj);
            z2 += expf(v.z - mj); z3 += expf(v.w - mj);
        }
        __syncthreads();
        scr[h][j] = (z0 + z1) + (z2 + z3);
        __syncthreads();
        if (h == 0) {
            s_m[j] = mj;
            s_z[j] = 1.f / (scr[0][j] + scr[1][j]);
        }
        __syncthreads();
    }

    // ---- prologue 2: persistent B fragments for BOTH col-sets (f16) ----
    // Shared k-convention with A: chunk ck, group g, elem i <-> k = ck*32+g*8+i.
    f16x8 bfA[8], bfB[8];
    #pragma unroll
    for (int ck = 0; ck < 8; ++ck) {
        #pragma unroll
        for (int i = 0; i < 8; ++i) {
            const int k = ck * 32 + g * 8 + i;
            const float* wk = weight + (size_t)k * Sn;
            bfA[ck][i] = (_Float16)(expf(wk[cA] - s_m[k]) * s_z[k]);
            bfB[ck][i] = (_Float16)(expf(wk[cB] - s_m[k]) * s_z[k]);
        }
    }
    // all-ones B operand: D = sum_k A[m,k] -> l1 in reg0 of EVERY lane
    const f16x8 ones8 = {(_Float16)1.f, (_Float16)1.f, (_Float16)1.f, (_Float16)1.f,
                         (_Float16)1.f, (_Float16)1.f, (_Float16)1.f, (_Float16)1.f};

    // ---- prologue 3: initial state softmax -> w~_0 image, e_1 ----
    const float* em = emission + (size_t)b * Tn * Sn + c32;
    float*       op = out      + (size_t)b * Tn * Sn + c32;
    {
        float i0 = init[lane], i1 = init[lane + 64],
              i2 = init[lane + 128], i3 = init[lane + 192];
        float mx = fmaxf(fmaxf(i0, i1), fmaxf(i2, i3));
        #pragma unroll
        for (int o = 32; o >= 1; o >>= 1) mx = fmaxf(mx, __shfl_xor(mx, o));
        float zz = expf(i0 - mx) + expf(i1 - mx) + expf(i2 - mx) + expf(i3 - mx);
        #pragma unroll
        for (int o = 32; o >= 1; o >>= 1) zz += __shfl_xor(zz, o);
        float u  = expf(init[c32] - mx) / zz;
        float w0 = u * em[0];
        if (lane >= 32) wf16[0][c32] = (_Float16)w0;
    }
    float enext = em[Sn];          // e_1[c32]
    __syncthreads();

#define MFMA(A, B, D) __builtin_amdgcn_mfma_f32_16x16x32_f16((A), (B), (D), 0, 0, 0)

    #pragma unroll 1
    for (int t = 0; t < Tn; ++t) {
        const int p = t & 1;

        // A fragments: w~_t image broadcast into all 16 M-rows (8 b128 reads)
        f16x8 af[8];
        #pragma unroll
        for (int ck = 0; ck < 8; ++ck)
            af[ck] = *reinterpret_cast<const f16x8*>(&wf16[p][ck * 32 + g * 8]);

        // y (32 cols, 4 chains) and l1 (ones-column, 2 chains) on the matrix pipe
        f32x4 dA0 = {0.f,0.f,0.f,0.f}, dA1 = {0.f,0.f,0.f,0.f};
        f32x4 dB0 = {0.f,0.f,0.f,0.f}, dB1 = {0.f,0.f,0.f,0.f};
        f32x4 dS0 = {0.f,0.f,0.f,0.f}, dS1 = {0.f,0.f,0.f,0.f};
        dA0 = MFMA(af[0], bfA[0], dA0); dB0 = MFMA(af[0], bfB[0], dB0); dS0 = MFMA(af[0], ones8, dS0);
        dA1 = MFMA(af[4], bfA[4], dA1); dB1 = MFMA(af[4], bfB[4], dB1); dS1 = MFMA(af[4], ones8, dS1);
        dA0 = MFMA(af[1], bfA[1], dA0); dB0 = MFMA(af[1], bfB[1], dB0); dS0 = MFMA(af[1], ones8, dS0);
        dA1 = MFMA(af[5], bfA[5], dA1); dB1 = MFMA(af[5], bfB[5], dB1); dS1 = MFMA(af[5], ones8, dS1);
        dA0 = MFMA(af[2], bfA[2], dA0); dB0 = MFMA(af[2], bfB[2], dB0); dS0 = MFMA(af[2], ones8, dS0);
        dA1 = MFMA(af[6], bfA[6], dA1); dB1 = MFMA(af[6], bfB[6], dB1); dS1 = MFMA(af[6], ones8, dS1);
        dA0 = MFMA(af[3], bfA[3], dA0); dB0 = MFMA(af[3], bfB[3], dB0); dS0 = MFMA(af[3], ones8, dS0);
        dA1 = MFMA(af[7], bfA[7], dA1); dB1 = MFMA(af[7], bfB[7], dB1); dS1 = MFMA(af[7], ones8, dS1);

        // row-broadcast A => reg0 holds y[col] / l1 in every lane
        float y  = ((lane & 16) == 0) ? (dA0[0] + dA1[0]) : (dB0[0] + dB1[0]);
        float l1 = fmaxf(dS0[0] + dS1[0], EPS);

        // exact power-of-2 rescale from THIS step's l1
        uint32_t ebits = __float_as_uint(l1) & 0x7f800000u;
        float sigma = __uint_as_float(0x7f000000u - ebits);

        // Bayes update + image write (lanes >= 32), pre-barrier critical tail
        float wn = (y * sigma) * enext;          // w~_{t+1}[c32]
        if (lane >= 32) wf16[p ^ 1][c32] = (_Float16)wn;

        // output store (lanes < 32) — off the critical path, vmcnt untouched
        if (lane < 32) op[(size_t)t * Sn] = y * (1.f / l1);

        // prefetch e_{t+2}
        const int tp = (t + 2 < Tn) ? (t + 2) : (Tn - 1);
        const float e2 = em[(size_t)tp * Sn];
        enext = e2;

        wg_barrier_lds();     // single lgkm-only barrier per step
    }

#undef MFMA
}

} // namespace

extern "C" void kernel_launch(void* const* d_in, const int* in_sizes, int n_in,
                              void* d_out, int out_size, void* d_ws, size_t ws_size,
                              hipStream_t stream) {
    const float* emission = (const float*)d_in[0];
    const float* weight   = (const float*)d_in[1];
    const float* init     = (const float*)d_in[2];
    float* outp = (float*)d_out;
    const int Bn = in_sizes[0] / (Tn * Sn);   // 128 for the reference shapes

    hipLaunchKernelGGL(hmm_kernel, dim3(Bn), dim3(512), 0, stream,
                       emission, weight, init, outp);
}

// Round 15
// 296.245 us; speedup vs baseline: 3.9394x; 1.1357x over previous
//
#include <hip/hip_runtime.h>
#include <stdint.h>

namespace {

constexpr int Tn = 512;
constexpr int Sn = 256;
constexpr float EPS = 1e-12f;

typedef _Float16 f16x8 __attribute__((ext_vector_type(8)));
typedef float    f32x4 __attribute__((ext_vector_type(4)));

// Barrier that drains ONLY lgkmcnt (LDS), never vmcnt (T4 pattern).
__device__ __forceinline__ void wg_barrier_lds() {
    asm volatile("s_waitcnt lgkmcnt(0)" ::: "memory");
    __builtin_amdgcn_s_barrier();
}

__launch_bounds__(256, 1)
__global__ void hmm_kernel(const float* __restrict__ emission,  // [B,T,S]
                           const float* __restrict__ weight,    // [S,S]
                           const float* __restrict__ init,      // [S]
                           float* __restrict__ out)             // [B,T,S]
{
    const int tid  = threadIdx.x;      // 0..255 == carried column
    const int wv   = tid >> 6;         // wave 0..3: owns cols 64wv .. 64wv+63
    const int lane = tid & 63;
    const int g    = lane >> 4;        // k-lane-group 0..3 (also my col-set)
    const int jj   = lane & 15;
    const int b    = blockIdx.x;       // batch row

    __shared__ __align__(16) _Float16 wf16[2][Sn];   // dbuf w~ image (f16)
    __shared__ __align__(16) float    s_m[Sn];
    __shared__ __align__(16) float    s_z[Sn];

    // ---- prologue 1: transition softmax row stats (thread j owns row j) ----
    {
        const float* wr = weight + (size_t)tid * Sn;
        float m = -3.402823466e38f;
        #pragma unroll 4
        for (int i = 0; i < Sn; i += 4) {
            float4 v = *reinterpret_cast<const float4*>(wr + i);
            m = fmaxf(m, fmaxf(fmaxf(v.x, v.y), fmaxf(v.z, v.w)));
        }
        float z0 = 0.f, z1 = 0.f, z2 = 0.f, z3 = 0.f;
        #pragma unroll 4
        for (int i = 0; i < Sn; i += 4) {
            float4 v = *reinterpret_cast<const float4*>(wr + i);
            z0 += expf(v.x - m); z1 += expf(v.y - m);
            z2 += expf(v.z - m); z3 += expf(v.w - m);
        }
        s_m[tid] = m;
        s_z[tid] = 1.f / ((z0 + z1) + (z2 + z3));
        __syncthreads();
    }

    // ---- prologue 2: persistent B fragments, 4 col-sets per wave (f16) ----
    // Shared k-convention with A: chunk ck, group g, elem i <-> k = ck*32+g*8+i.
    // bf[s][ck] covers column 64*wv + 16*s + jj.
    f16x8 bf[4][8];
    #pragma unroll
    for (int s = 0; s < 4; ++s) {
        const int col = 64 * wv + 16 * s + jj;
        #pragma unroll
        for (int ck = 0; ck < 8; ++ck) {
            #pragma unroll
            for (int i = 0; i < 8; ++i) {
                const int k = ck * 32 + g * 8 + i;
                bf[s][ck][i] =
                    (_Float16)(expf(weight[(size_t)k * Sn + col] - s_m[k]) * s_z[k]);
            }
        }
    }
    // all-ones B operand: D = sum_k A[m,k] -> l1 in reg0 of EVERY lane
    const f16x8 ones8 = {(_Float16)1.f, (_Float16)1.f, (_Float16)1.f, (_Float16)1.f,
                         (_Float16)1.f, (_Float16)1.f, (_Float16)1.f, (_Float16)1.f};

    // ---- prologue 3: initial state softmax -> w~_0 image, e_1 ----
    const float* em = emission + (size_t)b * Tn * Sn + tid;
    float*       op = out      + (size_t)b * Tn * Sn + tid;
    {
        float i0 = init[lane], i1 = init[lane + 64],
              i2 = init[lane + 128], i3 = init[lane + 192];
        float mx = fmaxf(fmaxf(i0, i1), fmaxf(i2, i3));
        #pragma unroll
        for (int o = 32; o >= 1; o >>= 1) mx = fmaxf(mx, __shfl_xor(mx, o));
        float zz = expf(i0 - mx) + expf(i1 - mx) + expf(i2 - mx) + expf(i3 - mx);
        #pragma unroll
        for (int o = 32; o >= 1; o >>= 1) zz += __shfl_xor(zz, o);
        float u  = expf(init[tid] - mx) / zz;
        float w0 = u * em[0];
        wf16[0][tid] = (_Float16)w0;
    }
    float enext = em[Sn];          // e_1[tid]
    __syncthreads();

#define MFMA(A, B, D) __builtin_amdgcn_mfma_f32_16x16x32_f16((A), (B), (D), 0, 0, 0)

    #pragma unroll 1
    for (int t = 0; t < Tn; ++t) {
        const int p = t & 1;

        // 5 MFMA chains (4 col-sets + ones), one shared af read per k-chunk
        f32x4 d0 = {0.f,0.f,0.f,0.f}, d1 = {0.f,0.f,0.f,0.f};
        f32x4 d2 = {0.f,0.f,0.f,0.f}, d3 = {0.f,0.f,0.f,0.f};
        f32x4 dS = {0.f,0.f,0.f,0.f};
        #pragma unroll
        for (int ck = 0; ck < 8; ++ck) {
            const f16x8 a =
                *reinterpret_cast<const f16x8*>(&wf16[p][ck * 32 + g * 8]);
            d0 = MFMA(a, bf[0][ck], d0);
            d1 = MFMA(a, bf[1][ck], d1);
            d2 = MFMA(a, bf[2][ck], d2);
            d3 = MFMA(a, bf[3][ck], d3);
            dS = MFMA(a, ones8, dS);
        }

        // row-broadcast A => reg0 of each chain holds y[64wv+16s+jj];
        // my carried column tid = 64wv + 16g + jj  =>  pick chain s = g.
        float y  = (g == 0) ? d0[0] : (g == 1) ? d1[0] : (g == 2) ? d2[0] : d3[0];
        float l1 = fmaxf(dS[0], EPS);

        // exact power-of-2 rescale from THIS step's l1
        uint32_t ebits = __float_as_uint(l1) & 0x7f800000u;
        float sigma = __uint_as_float(0x7f000000u - ebits);

        // Bayes update + image write (critical tail)
        float wn = (y * sigma) * enext;          // w~_{t+1}[tid]
        wf16[p ^ 1][tid] = (_Float16)wn;

        // output store — off the lgkm path, vmcnt untouched
        op[(size_t)t * Sn] = y * (1.f / l1);

        // prefetch e_{t+2}
        const int tp = (t + 2 < Tn) ? (t + 2) : (Tn - 1);
        enext = em[(size_t)tp * Sn];

        wg_barrier_lds();     // single lgkm-only barrier per step
    }

#undef MFMA
}

} // namespace

extern "C" void kernel_launch(void* const* d_in, const int* in_sizes, int n_in,
                              void* d_out, int out_size, void* d_ws, size_t ws_size,
                              hipStream_t stream) {
    const float* emission = (const float*)d_in[0];
    const float* weight   = (const float*)d_in[1];
    const float* init     = (const float*)d_in[2];
    float* outp = (float*)d_out;
    const int Bn = in_sizes[0] / (Tn * Sn);   // 128 for the reference shapes

    hipLaunchKernelGGL(hmm_kernel, dim3(Bn), dim3(256), 0, stream,
                       emission, weight, init, outp);
}

// Round 16
// 279.703 us; speedup vs baseline: 4.1723x; 1.0591x over previous
//
#include <hip/hip_runtime.h>
#include <stdint.h>

namespace {

constexpr int Tn = 512;
constexpr int Sn = 256;
constexpr float EPS = 1e-12f;

typedef _Float16 f16x8 __attribute__((ext_vector_type(8)));
typedef float    f32x4 __attribute__((ext_vector_type(4)));

// Barrier that drains ONLY lgkmcnt (LDS), never vmcnt (T4 pattern).
__device__ __forceinline__ void wg_barrier_lds() {
    asm volatile("s_waitcnt lgkmcnt(0)" ::: "memory");
    __builtin_amdgcn_s_barrier();
}

__launch_bounds__(256, 1)
__global__ void hmm_kernel(const float* __restrict__ emission,  // [B,T,S]
                           const float* __restrict__ weight,    // [S,S]
                           const float* __restrict__ init,      // [S]
                           float* __restrict__ out)             // [B,T,S]
{
    const int tid  = threadIdx.x;      // 0..255 == carried column
    const int wv   = tid >> 6;         // wave 0..3: owns cols 64wv .. 64wv+63
    const int lane = tid & 63;
    const int g    = lane >> 4;        // k-lane-group 0..3 (also my col-set)
    const int jj   = lane & 15;
    const int b    = blockIdx.x;       // batch row

    __shared__ __align__(16) _Float16 wf16[2][Sn];   // dbuf w~ image (f16)
    __shared__ __align__(16) float    s_m[Sn];
    __shared__ __align__(16) float    s_z[Sn];

    // ---- prologue 1: transition softmax row stats (thread j owns row j) ----
    {
        const float* wr = weight + (size_t)tid * Sn;
        float m = -3.402823466e38f;
        #pragma unroll 4
        for (int i = 0; i < Sn; i += 4) {
            float4 v = *reinterpret_cast<const float4*>(wr + i);
            m = fmaxf(m, fmaxf(fmaxf(v.x, v.y), fmaxf(v.z, v.w)));
        }
        float z0 = 0.f, z1 = 0.f, z2 = 0.f, z3 = 0.f;
        #pragma unroll 4
        for (int i = 0; i < Sn; i += 4) {
            float4 v = *reinterpret_cast<const float4*>(wr + i);
            z0 += expf(v.x - m); z1 += expf(v.y - m);
            z2 += expf(v.z - m); z3 += expf(v.w - m);
        }
        s_m[tid] = m;
        s_z[tid] = 1.f / ((z0 + z1) + (z2 + z3));
        __syncthreads();
    }

    // ---- prologue 2: persistent B fragments, 4 col-sets per wave (f16) ----
    // Shared k-convention with A: chunk ck, group g, elem i <-> k = ck*32+g*8+i.
    // bf[s][ck] covers column 64*wv + 16*s + jj.
    f16x8 bf[4][8];
    #pragma unroll
    for (int s = 0; s < 4; ++s) {
        const int col = 64 * wv + 16 * s + jj;
        #pragma unroll
        for (int ck = 0; ck < 8; ++ck) {
            #pragma unroll
            for (int i = 0; i < 8; ++i) {
                const int k = ck * 32 + g * 8 + i;
                bf[s][ck][i] =
                    (_Float16)(expf(weight[(size_t)k * Sn + col] - s_m[k]) * s_z[k]);
            }
        }
    }
    // all-ones B operand: D = sum_k A[m,k] -> l1 in reg0 of EVERY lane
    const f16x8 ones8 = {(_Float16)1.f, (_Float16)1.f, (_Float16)1.f, (_Float16)1.f,
                         (_Float16)1.f, (_Float16)1.f, (_Float16)1.f, (_Float16)1.f};

    // ---- prologue 3: initial state softmax -> w~_0 image, e_1 ----
    const float* em = emission + (size_t)b * Tn * Sn + tid;
    float*       op = out      + (size_t)b * Tn * Sn + tid;
    {
        float i0 = init[lane], i1 = init[lane + 64],
              i2 = init[lane + 128], i3 = init[lane + 192];
        float mx = fmaxf(fmaxf(i0, i1), fmaxf(i2, i3));
        #pragma unroll
        for (int o = 32; o >= 1; o >>= 1) mx = fmaxf(mx, __shfl_xor(mx, o));
        float zz = expf(i0 - mx) + expf(i1 - mx) + expf(i2 - mx) + expf(i3 - mx);
        #pragma unroll
        for (int o = 32; o >= 1; o >>= 1) zz += __shfl_xor(zz, o);
        float u  = expf(init[tid] - mx) / zz;
        float w0 = u * em[0];
        wf16[0][tid] = (_Float16)w0;
    }
    float enext = em[Sn];          // e_1[tid]
    __syncthreads();

#define MFMA(A, B, D) __builtin_amdgcn_mfma_f32_16x16x32_f16((A), (B), (D), 0, 0, 0)

    #pragma unroll 1
    for (int t = 0; t < Tn; ++t) {
        const int p = t & 1;

        // (1) load ALL af fragments first — 8 ds_read_b128 in flight at once.
        // We are grid-limited (1 block/CU), so the extra 32 VGPRs are free;
        // without this the allocator serialized read->wait->MFMA 8 times.
        f16x8 af[8];
        #pragma unroll
        for (int ck = 0; ck < 8; ++ck)
            af[ck] = *reinterpret_cast<const f16x8*>(&wf16[p][ck * 32 + g * 8]);

        // (2) pin: no MFMA may be scheduled before the loads are all issued
        __builtin_amdgcn_sched_barrier(0);

        // (3) 5 MFMA chains (4 col-sets + ones)
        f32x4 d0 = {0.f,0.f,0.f,0.f}, d1 = {0.f,0.f,0.f,0.f};
        f32x4 d2 = {0.f,0.f,0.f,0.f}, d3 = {0.f,0.f,0.f,0.f};
        f32x4 dS = {0.f,0.f,0.f,0.f};
        #pragma unroll
        for (int ck = 0; ck < 8; ++ck) {
            d0 = MFMA(af[ck], bf[0][ck], d0);
            d1 = MFMA(af[ck], bf[1][ck], d1);
            d2 = MFMA(af[ck], bf[2][ck], d2);
            d3 = MFMA(af[ck], bf[3][ck], d3);
            dS = MFMA(af[ck], ones8, dS);
        }

        // row-broadcast A => reg0 of each chain holds y[64wv+16s+jj];
        // my carried column tid = 64wv + 16g + jj  =>  pick chain s = g.
        float y  = (g == 0) ? d0[0] : (g == 1) ? d1[0] : (g == 2) ? d2[0] : d3[0];
        float l1 = fmaxf(dS[0], EPS);

        // exact power-of-2 rescale from THIS step's l1
        uint32_t ebits = __float_as_uint(l1) & 0x7f800000u;
        float sigma = __uint_as_float(0x7f000000u - ebits);

        // Bayes update + image write (critical tail)
        float wn = (y * sigma) * enext;          // w~_{t+1}[tid]
        wf16[p ^ 1][tid] = (_Float16)wn;

        // output store — off the lgkm path, vmcnt untouched
        op[(size_t)t * Sn] = y * (1.f / l1);

        // prefetch e_{t+2}
        const int tp = (t + 2 < Tn) ? (t + 2) : (Tn - 1);
        enext = em[(size_t)tp * Sn];

        wg_barrier_lds();     // single lgkm-only barrier per step
    }

#undef MFMA
}

} // namespace

extern "C" void kernel_launch(void* const* d_in, const int* in_sizes, int n_in,
                              void* d_out, int out_size, void* d_ws, size_t ws_size,
                              hipStream_t stream) {
    const float* emission = (const float*)d_in[0];
    const float* weight   = (const float*)d_in[1];
    const float* init     = (const float*)d_in[2];
    float* outp = (float*)d_out;
    const int Bn = in_sizes[0] / (Tn * Sn);   // 128 for the reference shapes

    hipLaunchKernelGGL(hmm_kernel, dim3(Bn), dim3(256), 0, stream,
                       emission, weight, init, outp);
}